// Round 5
// baseline (476.596 us; speedup 1.0000x reference)
//
#include <hip/hip_runtime.h>
#include <hip/hip_bf16.h>

#define NN 50000
#define NE 800000
#define FIN 128
#define HD 64
#define NC 40
#define NB 196      // ceil(NN/256)
#define RSPAN 6250  // NN/8 (dst range per blockIdx&7 class)

typedef __hip_bfloat16 bf16;

// uniform-lane broadcast via v_readlane (SGPR result, no LDS pipe)
__device__ __forceinline__ float bcastf(float v, int l){
  return __uint_as_float((unsigned)__builtin_amdgcn_readlane((int)__float_as_uint(v), l));
}

// accumulate 8 bf16 (one uint4) into fp32 bank
__device__ __forceinline__ void acc8(float* a, uint4 v){
  a[0] += __uint_as_float(v.x << 16); a[1] += __uint_as_float(v.x & 0xffff0000u);
  a[2] += __uint_as_float(v.y << 16); a[3] += __uint_as_float(v.y & 0xffff0000u);
  a[4] += __uint_as_float(v.z << 16); a[5] += __uint_as_float(v.z & 0xffff0000u);
  a[6] += __uint_as_float(v.w << 16); a[7] += __uint_as_float(v.w & 0xffff0000u);
}

// counters padded to 1 per 64B line (d<<4): breaks same-line atomic serialization
__global__ void k_count(const int* __restrict__ ei, int* __restrict__ cntp){
  int e = blockIdx.x*256 + threadIdx.x;
  if (e < NE) atomicAdd(&cntp[ei[NE + e] << 4], 1);
}

__global__ void k_bsum(const int* __restrict__ cntp, int* __restrict__ bsum){
  const int t = threadIdx.x;
  const int i = blockIdx.x*256 + t;
  int v = (i < NN) ? cntp[i << 4] : 0;
  #pragma unroll
  for (int off = 32; off; off >>= 1) v += __shfl_xor(v, off, 64);
  __shared__ int sw[4];
  if ((t & 63) == 0) sw[t >> 6] = v;
  __syncthreads();
  if (t == 0) bsum[blockIdx.x] = sw[0] + sw[1] + sw[2] + sw[3];
}

__global__ void k_bscan(const int* __restrict__ bsum, int* __restrict__ boff){
  __shared__ int sh[256];
  const int t = threadIdx.x;
  int v = (t < NB) ? bsum[t] : 0;
  sh[t] = v;
  __syncthreads();
  #pragma unroll
  for (int off = 1; off < 256; off <<= 1){
    int a = (t >= off) ? sh[t - off] : 0;
    __syncthreads();
    sh[t] += a;
    __syncthreads();
  }
  if (t < NB) boff[t] = sh[t] - v;   // exclusive
}

__global__ void k_rowptr(const int* __restrict__ cntp, const int* __restrict__ boff,
                         int* __restrict__ rowptr, int* __restrict__ cursorp){
  __shared__ int sh[256];
  const int t = threadIdx.x;
  const int i = blockIdx.x*256 + t;
  int v = (i < NN) ? cntp[i << 4] : 0;
  sh[t] = v;
  __syncthreads();
  #pragma unroll
  for (int off = 1; off < 256; off <<= 1){
    int a = (t >= off) ? sh[t - off] : 0;
    __syncthreads();
    sh[t] += a;
    __syncthreads();
  }
  if (i < NN){
    int excl = sh[t] - v + boff[blockIdx.x];
    rowptr[i] = excl;
    cursorp[i << 4] = excl;
  }
  if (i == 0) rowptr[NN] = NE;
}

// range-filtered scatter: block b reads edge-chunk b>>3, keeps dst in range b&7.
// esrc writes for one range come from one blockIdx-class -> lines dirty fully
// within one L2 instead of 4B/line across 8 XCDs.
__global__ void k_fill(const int* __restrict__ ei, int* __restrict__ cursorp,
                       int* __restrict__ esrc){
  const int chunk = blockIdx.x >> 3;
  const int lo    = (blockIdx.x & 7) * RSPAN;
  const int hi    = lo + RSPAN;
  int e = chunk * 2048 + threadIdx.x;
  #pragma unroll
  for (int j = 0; j < 8; ++j, e += 256){
    if (e < NE){
      const int d = ei[NE + e];
      if (d >= lo && d < hi){
        const int p = atomicAdd(&cursorp[d << 4], 1);
        esrc[p] = ei[e];
      }
    }
  }
}

// h0 = bf16(x_h @ W_init + b_init) ; hyp = bf16(tanh(pos @ W_pos + b_pos))
__global__ __launch_bounds__(256) void k_init(
    const float* __restrict__ x, const float* __restrict__ pos,
    const float* __restrict__ Wi, const float* __restrict__ bi,
    const float* __restrict__ Wp, const float* __restrict__ bp,
    bf16* __restrict__ h0b, bf16* __restrict__ hypb){
  const int lane = threadIdx.x & 63;
  const int wid  = blockIdx.x * 4 + (threadIdx.x >> 6);
  const int nw   = gridDim.x * 4;
  float wi[FIN];
  #pragma unroll
  for (int k = 0; k < FIN; ++k) wi[k] = Wi[k*HD + lane];
  float wp[16];
  #pragma unroll
  for (int k = 0; k < 16; ++k) wp[k] = Wp[k*HD + lane];
  const float bib = bi[lane];
  const float bpb = bp[lane];
  for (int n = wid; n < NN; n += nw){
    const float* xr = x + (size_t)n * FIN;
    float x0 = xr[lane];
    float x1 = xr[64 + lane];
    float pv = (lane < 16) ? pos[n*16 + lane] : 0.f;
    float acc = bib;
    #pragma unroll
    for (int k = 0; k < 64; ++k){
      acc += bcastf(x0, k) * wi[k];
      acc += bcastf(x1, k) * wi[64 + k];
    }
    float ap = bpb;
    #pragma unroll
    for (int k = 0; k < 16; ++k) ap += bcastf(pv, k) * wp[k];
    h0b[(size_t)n*HD + lane]  = __float2bfloat16(acc);
    hypb[(size_t)n*HD + lane] = __float2bfloat16(tanhf(ap));
  }
}

// Fused SAGE layer: hout = [relu]( mean_j(h_j)@Wl + h_n@Wr + b (+hyp) ), bf16 io.
// Wave per node (grid-stride). Gather lanes = eslot(0..7) x fq(0..7); one uint4
// load = 8 bf16 feats of one neighbor row -> 8 rows per instruction (1KB/wave).
// Butterfly-reduce over eslot; both matvecs in-register via readlane broadcasts.
__global__ __launch_bounds__(256) void k_gat(
    const bf16* __restrict__ hin, bf16* __restrict__ hout,
    const bf16* __restrict__ hypb,
    const int* __restrict__ rowptr, const int* __restrict__ esrc,
    const float* __restrict__ Wl, const float* __restrict__ Wr,
    const float* __restrict__ bc, const int use_hyp){
  const int lane  = threadIdx.x & 63;
  const int wid   = blockIdx.x * 4 + (threadIdx.x >> 6);
  const int nw    = gridDim.x * 4;
  const int fq    = lane & 7;
  const int eslot = lane >> 3;
  float wl[HD], wr[HD];
  #pragma unroll
  for (int k = 0; k < HD; ++k){
    wl[k] = Wl[k*HD + lane];
    wr[k] = Wr[k*HD + lane];
  }
  const float bb = bc[lane];
  for (int n = wid; n < NN; n += nw){
    const int r0 = rowptr[n], r1 = rowptr[n + 1];
    float a0[8] = {0,0,0,0,0,0,0,0};
    float a1[8] = {0,0,0,0,0,0,0,0};
    for (int base = r0; base < r1; base += 64){
      const int rem  = r1 - base;
      const int cdeg = rem < 64 ? rem : 64;
      const int sidx = (lane < cdeg) ? esrc[base + lane] : 0;
      const int rounds = (cdeg + 7) >> 3;
      for (int i = 0; i < rounds; i += 2){
        const int e0 = i*8 + eslot;
        const int e1 = e0 + 8;
        // shuffles run on the FULL wave (source-lane validity); loads predicated
        const int s0 = __shfl(sidx, e0, 64);
        const int s1 = __shfl(sidx, e1 & 63, 64);
        if (e0 < cdeg){
          const uint4 v = ((const uint4*)(hin + (size_t)s0*HD))[fq];
          acc8(a0, v);
        }
        if (e1 < cdeg){
          const uint4 v = ((const uint4*)(hin + (size_t)s1*HD))[fq];
          acc8(a1, v);
        }
      }
    }
    #pragma unroll
    for (int j = 0; j < 8; ++j){
      float s = a0[j] + a1[j];
      s += __shfl_xor(s, 8, 64);
      s += __shfl_xor(s, 16, 64);
      s += __shfl_xor(s, 32, 64);
      a0[j] = s;   // every lane now holds full sum for feats [fq*8+j] of its fq group
    }
    const float hv = __bfloat162float(hin[(size_t)n*HD + lane]);
    float macc = 0.f, racc = bb;
    #pragma unroll
    for (int k = 0; k < HD; ++k){
      macc += bcastf(a0[k & 7], k >> 3) * wl[k];  // agg[k] lives in lane k>>3, reg k&7
      racc += bcastf(hv, k) * wr[k];
    }
    const int deg = r1 - r0;
    const float inv = deg > 0 ? 1.f / (float)deg : 0.f;
    float o = macc * inv + racc;
    if (use_hyp){
      o += __bfloat162float(hypb[(size_t)n*HD + lane]);
      o = fmaxf(o, 0.f);
    }
    hout[(size_t)n*HD + lane] = __float2bfloat16(o);
  }
}

// emb = h @ W_last + b_last ; out = [emb ; log_softmax(emb)]
__global__ __launch_bounds__(256) void k_final(
    const bf16* __restrict__ hin, const float* __restrict__ Wl,
    const float* __restrict__ bl, float* __restrict__ out){
  const int lane = threadIdx.x & 63;
  const int wid  = blockIdx.x * 4 + (threadIdx.x >> 6);
  const int nw   = gridDim.x * 4;
  const int c = lane < NC ? lane : 0;
  float w[HD];
  #pragma unroll
  for (int k = 0; k < HD; ++k) w[k] = Wl[k*NC + c];
  const float bb = bl[c];
  for (int n = wid; n < NN; n += nw){
    const float hv = __bfloat162float(hin[(size_t)n*HD + lane]);
    float acc = bb;
    #pragma unroll
    for (int k = 0; k < HD; ++k) acc += bcastf(hv, k) * w[k];
    float vmax = (lane < NC) ? acc : -3.4e38f;
    #pragma unroll
    for (int off = 32; off; off >>= 1)
      vmax = fmaxf(vmax, __shfl_xor(vmax, off, 64));
    float ex = (lane < NC) ? __expf(acc - vmax) : 0.f;
    float s = ex;
    #pragma unroll
    for (int off = 32; off; off >>= 1)
      s += __shfl_xor(s, off, 64);
    const float lsm = acc - vmax - __logf(s);
    if (lane < NC){
      out[(size_t)n*NC + lane]                 = acc;
      out[(size_t)NN*NC + (size_t)n*NC + lane] = lsm;
    }
  }
}

extern "C" void kernel_launch(void* const* d_in, const int* in_sizes, int n_in,
                              void* d_out, int out_size, void* d_ws, size_t ws_size,
                              hipStream_t stream){
  (void)in_sizes; (void)n_in; (void)out_size; (void)ws_size;
  const float* x_h    = (const float*)d_in[0];
  const float* pos    = (const float*)d_in[1];
  const int*   ei     = (const int*)  d_in[2];
  const float* W_pos  = (const float*)d_in[3];
  const float* b_pos  = (const float*)d_in[4];
  const float* W_init = (const float*)d_in[5];
  const float* b_init = (const float*)d_in[6];
  const float* W_l    = (const float*)d_in[7];
  const float* W_r    = (const float*)d_in[8];
  const float* b_conv = (const float*)d_in[9];
  const float* W_last = (const float*)d_in[10];
  const float* b_last = (const float*)d_in[11];
  float* out = (float*)d_out;

  char* p = (char*)d_ws;
  auto alloc = [&](size_t bytes)->char*{
    char* r = p; p += (bytes + 255) & ~(size_t)255; return r;
  };
  bf16* hb0    = (bf16*)alloc((size_t)NN*HD*2);
  bf16* hb1    = (bf16*)alloc((size_t)NN*HD*2);
  bf16* hypb   = (bf16*)alloc((size_t)NN*HD*2);
  int* cntp    = (int*)alloc((size_t)NN*16*4);
  int* cursorp = (int*)alloc((size_t)NN*16*4);
  int* rowptr  = (int*)alloc((size_t)(NN+1)*4);
  int* esrc    = (int*)alloc((size_t)NE*4);
  int* bsum    = (int*)alloc((size_t)NB*4);
  int* boff    = (int*)alloc((size_t)NB*4);

  hipMemsetAsync(cntp, 0, (size_t)NN*16*4, stream);
  k_count <<<(NE + 255)/256, 256, 0, stream>>>(ei, cntp);
  k_bsum  <<<NB, 256, 0, stream>>>(cntp, bsum);
  k_bscan <<<1, 256, 0, stream>>>(bsum, boff);
  k_rowptr<<<NB, 256, 0, stream>>>(cntp, boff, rowptr, cursorp);
  k_fill  <<<((NE + 2047)/2048)*8, 256, 0, stream>>>(ei, cursorp, esrc);
  k_init  <<<512, 256, 0, stream>>>(x_h, pos, W_init, b_init, W_pos, b_pos, hb0, hypb);

  k_gat<<<1024, 256, 0, stream>>>(hb0, hb1, hypb, rowptr, esrc,
                                  W_l,           W_r,           b_conv,        1);
  k_gat<<<1024, 256, 0, stream>>>(hb1, hb0, hypb, rowptr, esrc,
                                  W_l + HD*HD,   W_r + HD*HD,   b_conv + HD,   1);
  k_gat<<<1024, 256, 0, stream>>>(hb0, hb1, hypb, rowptr, esrc,
                                  W_l + 2*HD*HD, W_r + 2*HD*HD, b_conv + 2*HD, 0);
  k_final<<<512, 256, 0, stream>>>(hb1, W_last, b_last, out);
}

// Round 6
// 386.080 us; speedup vs baseline: 1.2344x; 1.2344x over previous
//
#include <hip/hip_runtime.h>
#include <hip/hip_bf16.h>

#define NN 50000
#define NE 800000
#define FIN 128
#define HD 64
#define NC 40
#define NB 196      // ceil(NN/256)
#define RSPAN 6250  // NN/8 (dst range per blockIdx&7 class)

typedef __hip_bfloat16 bf16;

// uniform-lane broadcast via v_readlane (SGPR result, no LDS pipe)
__device__ __forceinline__ float bcastf(float v, int l){
  return __uint_as_float((unsigned)__builtin_amdgcn_readlane((int)__float_as_uint(v), l));
}

// accumulate 8 bf16 (one uint4) into fp32 bank
__device__ __forceinline__ void acc8(float* a, uint4 v){
  a[0] += __uint_as_float(v.x << 16); a[1] += __uint_as_float(v.x & 0xffff0000u);
  a[2] += __uint_as_float(v.y << 16); a[3] += __uint_as_float(v.y & 0xffff0000u);
  a[4] += __uint_as_float(v.z << 16); a[5] += __uint_as_float(v.z & 0xffff0000u);
  a[6] += __uint_as_float(v.w << 16); a[7] += __uint_as_float(v.w & 0xffff0000u);
}

__device__ __forceinline__ unsigned pack2(float lo, float hi){
  union { bf16 b; unsigned short u; } a, b;
  a.b = __float2bfloat16(lo);
  b.b = __float2bfloat16(hi);
  return (unsigned)a.u | ((unsigned)b.u << 16);
}

// counters padded to 1 per 64B line (d<<4): breaks same-line atomic serialization
__global__ void k_count(const int* __restrict__ ei, int* __restrict__ cntp){
  int e = blockIdx.x*256 + threadIdx.x;
  if (e < NE) atomicAdd(&cntp[ei[NE + e] << 4], 1);
}

__global__ void k_bsum(const int* __restrict__ cntp, int* __restrict__ bsum){
  const int t = threadIdx.x;
  const int i = blockIdx.x*256 + t;
  int v = (i < NN) ? cntp[i << 4] : 0;
  #pragma unroll
  for (int off = 32; off; off >>= 1) v += __shfl_xor(v, off, 64);
  __shared__ int sw[4];
  if ((t & 63) == 0) sw[t >> 6] = v;
  __syncthreads();
  if (t == 0) bsum[blockIdx.x] = sw[0] + sw[1] + sw[2] + sw[3];
}

__global__ void k_bscan(const int* __restrict__ bsum, int* __restrict__ boff){
  __shared__ int sh[256];
  const int t = threadIdx.x;
  int v = (t < NB) ? bsum[t] : 0;
  sh[t] = v;
  __syncthreads();
  #pragma unroll
  for (int off = 1; off < 256; off <<= 1){
    int a = (t >= off) ? sh[t - off] : 0;
    __syncthreads();
    sh[t] += a;
    __syncthreads();
  }
  if (t < NB) boff[t] = sh[t] - v;   // exclusive
}

__global__ void k_rowptr(const int* __restrict__ cntp, const int* __restrict__ boff,
                         int* __restrict__ rowptr, int* __restrict__ cursorp){
  __shared__ int sh[256];
  const int t = threadIdx.x;
  const int i = blockIdx.x*256 + t;
  int v = (i < NN) ? cntp[i << 4] : 0;
  sh[t] = v;
  __syncthreads();
  #pragma unroll
  for (int off = 1; off < 256; off <<= 1){
    int a = (t >= off) ? sh[t - off] : 0;
    __syncthreads();
    sh[t] += a;
    __syncthreads();
  }
  if (i < NN){
    int excl = sh[t] - v + boff[blockIdx.x];
    rowptr[i] = excl;
    cursorp[i << 4] = excl;
  }
  if (i == 0) rowptr[NN] = NE;
}

// range-filtered scatter: block b reads edge-chunk b>>3, keeps dst in range b&7.
__global__ void k_fill(const int* __restrict__ ei, int* __restrict__ cursorp,
                       int* __restrict__ esrc){
  const int chunk = blockIdx.x >> 3;
  const int lo    = (blockIdx.x & 7) * RSPAN;
  const int hi    = lo + RSPAN;
  int e = chunk * 2048 + threadIdx.x;
  #pragma unroll
  for (int j = 0; j < 8; ++j, e += 256){
    if (e < NE){
      const int d = ei[NE + e];
      if (d >= lo && d < hi){
        const int p = atomicAdd(&cursorp[d << 4], 1);
        esrc[p] = ei[e];
      }
    }
  }
}

// h0 = bf16(x_h @ W_init + b_init) ; hyp = bf16(tanh(pos @ W_pos + b_pos))
__global__ __launch_bounds__(256) void k_init(
    const float* __restrict__ x, const float* __restrict__ pos,
    const float* __restrict__ Wi, const float* __restrict__ bi,
    const float* __restrict__ Wp, const float* __restrict__ bp,
    bf16* __restrict__ h0b, bf16* __restrict__ hypb){
  const int lane = threadIdx.x & 63;
  const int wid  = blockIdx.x * 4 + (threadIdx.x >> 6);
  const int nw   = gridDim.x * 4;
  float wi[FIN];
  #pragma unroll
  for (int k = 0; k < FIN; ++k) wi[k] = Wi[k*HD + lane];
  float wp[16];
  #pragma unroll
  for (int k = 0; k < 16; ++k) wp[k] = Wp[k*HD + lane];
  const float bib = bi[lane];
  const float bpb = bp[lane];
  for (int n = wid; n < NN; n += nw){
    const float* xr = x + (size_t)n * FIN;
    float x0 = xr[lane];
    float x1 = xr[64 + lane];
    float pv = (lane < 16) ? pos[n*16 + lane] : 0.f;
    float c0 = bib, c1 = 0.f, c2 = 0.f, c3 = 0.f;
    #pragma unroll
    for (int k = 0; k < 64; k += 4){
      c0 += bcastf(x0, k  ) * wi[k  ] + bcastf(x1, k  ) * wi[64 + k  ];
      c1 += bcastf(x0, k+1) * wi[k+1] + bcastf(x1, k+1) * wi[64 + k+1];
      c2 += bcastf(x0, k+2) * wi[k+2] + bcastf(x1, k+2) * wi[64 + k+2];
      c3 += bcastf(x0, k+3) * wi[k+3] + bcastf(x1, k+3) * wi[64 + k+3];
    }
    float ap = bpb;
    #pragma unroll
    for (int k = 0; k < 16; ++k) ap += bcastf(pv, k) * wp[k];
    h0b[(size_t)n*HD + lane]  = __float2bfloat16((c0 + c1) + (c2 + c3));
    hypb[(size_t)n*HD + lane] = __float2bfloat16(tanhf(ap));
  }
}

// dense transforms: y = h@Wl (bf16), z = h@Wr + b (+hyp) (bf16)
__global__ __launch_bounds__(256) void k_xform(
    const bf16* __restrict__ h, const float* __restrict__ Wl,
    const float* __restrict__ Wr, const float* __restrict__ bc,
    const bf16* __restrict__ hypb, const int use_hyp,
    bf16* __restrict__ y, bf16* __restrict__ z){
  const int lane = threadIdx.x & 63;
  const int wid  = blockIdx.x * 4 + (threadIdx.x >> 6);
  const int nw   = gridDim.x * 4;
  float wl[HD], wr[HD];
  #pragma unroll
  for (int k = 0; k < HD; ++k){
    wl[k] = Wl[k*HD + lane];
    wr[k] = Wr[k*HD + lane];
  }
  const float bb = bc[lane];
  for (int n = wid; n < NN; n += nw){
    const float hv = __bfloat162float(h[(size_t)n*HD + lane]);
    float y0=0.f,y1=0.f,y2=0.f,y3=0.f;
    float z0=bb,z1=0.f,z2=0.f,z3=0.f;
    #pragma unroll
    for (int k = 0; k < HD; k += 4){
      const float s0 = bcastf(hv, k  );
      const float s1 = bcastf(hv, k+1);
      const float s2 = bcastf(hv, k+2);
      const float s3 = bcastf(hv, k+3);
      y0 += s0*wl[k];   z0 += s0*wr[k];
      y1 += s1*wl[k+1]; z1 += s1*wr[k+1];
      y2 += s2*wl[k+2]; z2 += s2*wr[k+2];
      y3 += s3*wl[k+3]; z3 += s3*wr[k+3];
    }
    float ay = (y0+y1)+(y2+y3);
    float az = (z0+z1)+(z2+z3);
    if (use_hyp) az += __bfloat162float(hypb[(size_t)n*HD + lane]);
    y[(size_t)n*HD + lane] = __float2bfloat16(ay);
    z[(size_t)n*HD + lane] = __float2bfloat16(az);
  }
}

// pure-memory gather: out = [relu]( sum_j y_j / deg + z )   (bf16 io)
// one wave per node; lane = eslot(0..7) x fq(0..7); one uint4 = 8 bf16 feats
// of one neighbor row -> 8 rows per load instruction (1 KB per wave round).
__global__ __launch_bounds__(256) void k_gather(
    const bf16* __restrict__ y, const bf16* __restrict__ z,
    const int* __restrict__ rowptr, const int* __restrict__ esrc,
    bf16* __restrict__ out, const int do_relu){
  const int lane  = threadIdx.x & 63;
  const int n     = blockIdx.x * 4 + (threadIdx.x >> 6);
  if (n >= NN) return;
  const int fq    = lane & 7;
  const int eslot = lane >> 3;
  const int r0 = rowptr[n], r1 = rowptr[n + 1];
  float a0[8] = {0,0,0,0,0,0,0,0};
  float a1[8] = {0,0,0,0,0,0,0,0};
  for (int base = r0; base < r1; base += 64){
    const int rem  = r1 - base;
    const int cdeg = rem < 64 ? rem : 64;
    const int sidx = (lane < cdeg) ? esrc[base + lane] : 0;
    const int rounds = (cdeg + 7) >> 3;
    for (int i = 0; i < rounds; i += 2){
      const int e0 = i*8 + eslot;
      const int e1 = e0 + 8;
      // shuffles on the FULL wave (source-lane validity); loads predicated
      const int s0 = __shfl(sidx, e0, 64);
      const int s1 = __shfl(sidx, e1 & 63, 64);
      if (e0 < cdeg){
        const uint4 v = ((const uint4*)(y + (size_t)s0*HD))[fq];
        acc8(a0, v);
      }
      if (e1 < cdeg){
        const uint4 v = ((const uint4*)(y + (size_t)s1*HD))[fq];
        acc8(a1, v);
      }
    }
  }
  #pragma unroll
  for (int j = 0; j < 8; ++j){
    float s = a0[j] + a1[j];
    s += __shfl_xor(s, 8, 64);
    s += __shfl_xor(s, 16, 64);
    s += __shfl_xor(s, 32, 64);
    a0[j] = s;   // all lanes of this fq group now hold feats [fq*8 .. fq*8+8)
  }
  if (eslot == 0){
    const int deg = r1 - r0;
    const float inv = deg > 0 ? 1.f / (float)deg : 0.f;
    const uint4 zv = ((const uint4*)(z + (size_t)n*HD))[fq];
    float zf[8];
    zf[0] = __uint_as_float(zv.x << 16); zf[1] = __uint_as_float(zv.x & 0xffff0000u);
    zf[2] = __uint_as_float(zv.y << 16); zf[3] = __uint_as_float(zv.y & 0xffff0000u);
    zf[4] = __uint_as_float(zv.z << 16); zf[5] = __uint_as_float(zv.z & 0xffff0000u);
    zf[6] = __uint_as_float(zv.w << 16); zf[7] = __uint_as_float(zv.w & 0xffff0000u);
    float o[8];
    #pragma unroll
    for (int j = 0; j < 8; ++j){
      o[j] = a0[j]*inv + zf[j];
      if (do_relu) o[j] = fmaxf(o[j], 0.f);
    }
    uint4 pv;
    pv.x = pack2(o[0], o[1]);
    pv.y = pack2(o[2], o[3]);
    pv.z = pack2(o[4], o[5]);
    pv.w = pack2(o[6], o[7]);
    ((uint4*)(out + (size_t)n*HD))[fq] = pv;
  }
}

// emb = h @ W_last + b_last ; out = [emb ; log_softmax(emb)]
__global__ __launch_bounds__(256) void k_final(
    const bf16* __restrict__ hin, const float* __restrict__ Wl,
    const float* __restrict__ bl, float* __restrict__ out){
  const int lane = threadIdx.x & 63;
  const int wid  = blockIdx.x * 4 + (threadIdx.x >> 6);
  const int nw   = gridDim.x * 4;
  const int c = lane < NC ? lane : 0;
  float w[HD];
  #pragma unroll
  for (int k = 0; k < HD; ++k) w[k] = Wl[k*NC + c];
  const float bb = bl[c];
  for (int n = wid; n < NN; n += nw){
    const float hv = __bfloat162float(hin[(size_t)n*HD + lane]);
    float c0 = bb, c1 = 0.f, c2 = 0.f, c3 = 0.f;
    #pragma unroll
    for (int k = 0; k < HD; k += 4){
      c0 += bcastf(hv, k  ) * w[k  ];
      c1 += bcastf(hv, k+1) * w[k+1];
      c2 += bcastf(hv, k+2) * w[k+2];
      c3 += bcastf(hv, k+3) * w[k+3];
    }
    const float acc = (c0 + c1) + (c2 + c3);
    float vmax = (lane < NC) ? acc : -3.4e38f;
    #pragma unroll
    for (int off = 32; off; off >>= 1)
      vmax = fmaxf(vmax, __shfl_xor(vmax, off, 64));
    float ex = (lane < NC) ? __expf(acc - vmax) : 0.f;
    float s = ex;
    #pragma unroll
    for (int off = 32; off; off >>= 1)
      s += __shfl_xor(s, off, 64);
    const float lsm = acc - vmax - __logf(s);
    if (lane < NC){
      out[(size_t)n*NC + lane]                 = acc;
      out[(size_t)NN*NC + (size_t)n*NC + lane] = lsm;
    }
  }
}

extern "C" void kernel_launch(void* const* d_in, const int* in_sizes, int n_in,
                              void* d_out, int out_size, void* d_ws, size_t ws_size,
                              hipStream_t stream){
  (void)in_sizes; (void)n_in; (void)out_size; (void)ws_size;
  const float* x_h    = (const float*)d_in[0];
  const float* pos    = (const float*)d_in[1];
  const int*   ei     = (const int*)  d_in[2];
  const float* W_pos  = (const float*)d_in[3];
  const float* b_pos  = (const float*)d_in[4];
  const float* W_init = (const float*)d_in[5];
  const float* b_init = (const float*)d_in[6];
  const float* W_l    = (const float*)d_in[7];
  const float* W_r    = (const float*)d_in[8];
  const float* b_conv = (const float*)d_in[9];
  const float* W_last = (const float*)d_in[10];
  const float* b_last = (const float*)d_in[11];
  float* out = (float*)d_out;

  char* p = (char*)d_ws;
  auto alloc = [&](size_t bytes)->char*{
    char* r = p; p += (bytes + 255) & ~(size_t)255; return r;
  };
  bf16* hb0    = (bf16*)alloc((size_t)NN*HD*2);
  bf16* hb1    = (bf16*)alloc((size_t)NN*HD*2);
  bf16* yb     = (bf16*)alloc((size_t)NN*HD*2);
  bf16* hypb   = (bf16*)alloc((size_t)NN*HD*2);
  int* cntp    = (int*)alloc((size_t)NN*16*4);
  int* cursorp = (int*)alloc((size_t)NN*16*4);
  int* rowptr  = (int*)alloc((size_t)(NN+1)*4);
  int* esrc    = (int*)alloc((size_t)NE*4);
  int* bsum    = (int*)alloc((size_t)NB*4);
  int* boff    = (int*)alloc((size_t)NB*4);

  hipMemsetAsync(cntp, 0, (size_t)NN*16*4, stream);
  k_count <<<(NE + 255)/256, 256, 0, stream>>>(ei, cntp);
  k_bsum  <<<NB, 256, 0, stream>>>(cntp, bsum);
  k_bscan <<<1, 256, 0, stream>>>(bsum, boff);
  k_rowptr<<<NB, 256, 0, stream>>>(cntp, boff, rowptr, cursorp);
  k_fill  <<<((NE + 2047)/2048)*8, 256, 0, stream>>>(ei, cursorp, esrc);
  k_init  <<<1024, 256, 0, stream>>>(x_h, pos, W_init, b_init, W_pos, b_pos, hb0, hypb);

  bf16* cur = hb0;
  bf16* nxt = hb1;
  for (int l = 0; l < 3; ++l){
    const int last = (l == 2);
    // y -> yb ; z -> nxt (includes +hyp when not last layer)
    k_xform <<<1024, 256, 0, stream>>>(cur, W_l + l*HD*HD, W_r + l*HD*HD,
                                       b_conv + l*HD, hypb, !last, yb, nxt);
    // out -> in-place over nxt (z); relu when not last layer
    k_gather<<<(NN + 3)/4, 256, 0, stream>>>(yb, nxt, rowptr, esrc, nxt, !last);
    bf16* t = cur; cur = nxt; nxt = t;
  }
  k_final <<<512, 256, 0, stream>>>(cur, W_last, b_last, out);
}

// Round 7
// 351.230 us; speedup vs baseline: 1.3569x; 1.0992x over previous
//
#include <hip/hip_runtime.h>
#include <hip/hip_bf16.h>

#define NN 50000
#define NE 800000
#define FIN 128
#define HD 64
#define NC 40
#define NB 196      // ceil(NN/256)
#define RSPAN 6250  // NN/8 (dst range per blockIdx&7 class)

typedef __hip_bfloat16 bf16;
typedef __attribute__((ext_vector_type(8))) short bf16x8;   // 8 bf16 in 4 VGPRs
typedef __attribute__((ext_vector_type(4))) float f32x4;

// uniform-lane broadcast via v_readlane (SGPR result, no LDS pipe)
__device__ __forceinline__ float bcastf(float v, int l){
  return __uint_as_float((unsigned)__builtin_amdgcn_readlane((int)__float_as_uint(v), l));
}

// accumulate 8 bf16 (one uint4) into fp32 bank
__device__ __forceinline__ void acc8(float* a, uint4 v){
  a[0] += __uint_as_float(v.x << 16); a[1] += __uint_as_float(v.x & 0xffff0000u);
  a[2] += __uint_as_float(v.y << 16); a[3] += __uint_as_float(v.y & 0xffff0000u);
  a[4] += __uint_as_float(v.z << 16); a[5] += __uint_as_float(v.z & 0xffff0000u);
  a[6] += __uint_as_float(v.w << 16); a[7] += __uint_as_float(v.w & 0xffff0000u);
}

__device__ __forceinline__ unsigned pack2(float lo, float hi){
  union { bf16 b; unsigned short u; } a, b;
  a.b = __float2bfloat16(lo);
  b.b = __float2bfloat16(hi);
  return (unsigned)a.u | ((unsigned)b.u << 16);
}

__device__ __forceinline__ short f2bf_bits(float f){
  union { bf16 b; short s; } u;
  u.b = __float2bfloat16(f);
  return u.s;
}

// counters padded to 1 per 64B line (d<<4): breaks same-line atomic serialization
__global__ void k_count(const int* __restrict__ ei, int* __restrict__ cntp){
  int e = blockIdx.x*256 + threadIdx.x;
  if (e < NE) atomicAdd(&cntp[ei[NE + e] << 4], 1);
}

__global__ void k_bsum(const int* __restrict__ cntp, int* __restrict__ bsum){
  const int t = threadIdx.x;
  const int i = blockIdx.x*256 + t;
  int v = (i < NN) ? cntp[i << 4] : 0;
  #pragma unroll
  for (int off = 32; off; off >>= 1) v += __shfl_xor(v, off, 64);
  __shared__ int sw[4];
  if ((t & 63) == 0) sw[t >> 6] = v;
  __syncthreads();
  if (t == 0) bsum[blockIdx.x] = sw[0] + sw[1] + sw[2] + sw[3];
}

__global__ void k_bscan(const int* __restrict__ bsum, int* __restrict__ boff){
  __shared__ int sh[256];
  const int t = threadIdx.x;
  int v = (t < NB) ? bsum[t] : 0;
  sh[t] = v;
  __syncthreads();
  #pragma unroll
  for (int off = 1; off < 256; off <<= 1){
    int a = (t >= off) ? sh[t - off] : 0;
    __syncthreads();
    sh[t] += a;
    __syncthreads();
  }
  if (t < NB) boff[t] = sh[t] - v;   // exclusive
}

__global__ void k_rowptr(const int* __restrict__ cntp, const int* __restrict__ boff,
                         int* __restrict__ rowptr, int* __restrict__ cursorp){
  __shared__ int sh[256];
  const int t = threadIdx.x;
  const int i = blockIdx.x*256 + t;
  int v = (i < NN) ? cntp[i << 4] : 0;
  sh[t] = v;
  __syncthreads();
  #pragma unroll
  for (int off = 1; off < 256; off <<= 1){
    int a = (t >= off) ? sh[t - off] : 0;
    __syncthreads();
    sh[t] += a;
    __syncthreads();
  }
  if (i < NN){
    int excl = sh[t] - v + boff[blockIdx.x];
    rowptr[i] = excl;
    cursorp[i << 4] = excl;
  }
  if (i == 0) rowptr[NN] = NE;
}

// range-filtered scatter: block b reads edge-chunk b>>3, keeps dst in range b&7.
__global__ void k_fill(const int* __restrict__ ei, int* __restrict__ cursorp,
                       int* __restrict__ esrc){
  const int chunk = blockIdx.x >> 3;
  const int lo    = (blockIdx.x & 7) * RSPAN;
  const int hi    = lo + RSPAN;
  int e = chunk * 2048 + threadIdx.x;
  #pragma unroll
  for (int j = 0; j < 8; ++j, e += 256){
    if (e < NE){
      const int d = ei[NE + e];
      if (d >= lo && d < hi){
        const int p = atomicAdd(&cursorp[d << 4], 1);
        esrc[p] = ei[e];
      }
    }
  }
}

// h0 = bf16(x_h @ W_init + b_init) ; hyp = bf16(tanh(pos @ W_pos + b_pos))
__global__ __launch_bounds__(256) void k_init(
    const float* __restrict__ x, const float* __restrict__ pos,
    const float* __restrict__ Wi, const float* __restrict__ bi,
    const float* __restrict__ Wp, const float* __restrict__ bp,
    bf16* __restrict__ h0b, bf16* __restrict__ hypb){
  const int lane = threadIdx.x & 63;
  const int wid  = blockIdx.x * 4 + (threadIdx.x >> 6);
  const int nw   = gridDim.x * 4;
  float wi[FIN];
  #pragma unroll
  for (int k = 0; k < FIN; ++k) wi[k] = Wi[k*HD + lane];
  float wp[16];
  #pragma unroll
  for (int k = 0; k < 16; ++k) wp[k] = Wp[k*HD + lane];
  const float bib = bi[lane];
  const float bpb = bp[lane];
  for (int n = wid; n < NN; n += nw){
    const float* xr = x + (size_t)n * FIN;
    float x0 = xr[lane];
    float x1 = xr[64 + lane];
    float pv = (lane < 16) ? pos[n*16 + lane] : 0.f;
    float c0 = bib, c1 = 0.f, c2 = 0.f, c3 = 0.f;
    #pragma unroll
    for (int k = 0; k < 64; k += 4){
      c0 += bcastf(x0, k  ) * wi[k  ] + bcastf(x1, k  ) * wi[64 + k  ];
      c1 += bcastf(x0, k+1) * wi[k+1] + bcastf(x1, k+1) * wi[64 + k+1];
      c2 += bcastf(x0, k+2) * wi[k+2] + bcastf(x1, k+2) * wi[64 + k+2];
      c3 += bcastf(x0, k+3) * wi[k+3] + bcastf(x1, k+3) * wi[64 + k+3];
    }
    float ap = bpb;
    #pragma unroll
    for (int k = 0; k < 16; ++k) ap += bcastf(pv, k) * wp[k];
    h0b[(size_t)n*HD + lane]  = __float2bfloat16((c0 + c1) + (c2 + c3));
    hypb[(size_t)n*HD + lane] = __float2bfloat16(tanhf(ap));
  }
}

// MFMA dense transforms: y = h@Wl ; z = h@Wr + b (+hyp)   (bf16 io, fp32 accum)
// Wave per 16-node tile (NN = 16*3125 exactly). A: [m=lane&15][k=quad*8+j];
// B: [k=quad*8+j][n=lane&15]; C/D: col=lane&15, row=quad*4+reg (HW-verified).
// 8 col-tiles: ct 0..3 -> Wl (y cols 0..63), ct 4..7 -> Wr (z cols 0..63).
__global__ __launch_bounds__(256) void k_xform(
    const bf16* __restrict__ h, const float* __restrict__ Wl,
    const float* __restrict__ Wr, const float* __restrict__ bc,
    const bf16* __restrict__ hypb, const int use_hyp,
    bf16* __restrict__ y, bf16* __restrict__ z){
  const int lane = threadIdx.x & 63;
  const int quad = lane >> 4;
  const int col  = lane & 15;
  const int wid  = blockIdx.x * 4 + (threadIdx.x >> 6);
  const int nw   = gridDim.x * 4;

  bf16x8 bfr[8][2];
  #pragma unroll
  for (int ct = 0; ct < 8; ++ct){
    const float* W = (ct < 4) ? Wl : Wr;
    const int nc = (ct & 3) * 16 + col;
    #pragma unroll
    for (int kf = 0; kf < 2; ++kf)
      #pragma unroll
      for (int j = 0; j < 8; ++j)
        bfr[ct][kf][j] = f2bf_bits(W[(kf*32 + quad*8 + j)*HD + nc]);
  }
  float zb[4];
  #pragma unroll
  for (int c = 0; c < 4; ++c) zb[c] = bc[c*16 + col];

  for (int t = wid; t < NN/16; t += nw){
    const int n0 = t * 16;
    union { uint4 u; bf16x8 v; } a0, a1;
    a0.u = *(const uint4*)(h + (size_t)(n0 + col)*HD + quad*8);
    a1.u = *(const uint4*)(h + (size_t)(n0 + col)*HD + 32 + quad*8);
    f32x4 acc[8];
    #pragma unroll
    for (int c = 0; c < 4; ++c) acc[c] = (f32x4){0.f, 0.f, 0.f, 0.f};
    #pragma unroll
    for (int c = 0; c < 4; ++c) acc[4+c] = (f32x4){zb[c], zb[c], zb[c], zb[c]};
    #pragma unroll
    for (int ct = 0; ct < 8; ++ct){
      acc[ct] = __builtin_amdgcn_mfma_f32_16x16x32_bf16(a0.v, bfr[ct][0], acc[ct], 0, 0, 0);
      acc[ct] = __builtin_amdgcn_mfma_f32_16x16x32_bf16(a1.v, bfr[ct][1], acc[ct], 0, 0, 0);
    }
    #pragma unroll
    for (int reg = 0; reg < 4; ++reg){
      const int n = n0 + quad*4 + reg;
      #pragma unroll
      for (int c = 0; c < 4; ++c){
        y[(size_t)n*HD + c*16 + col] = __float2bfloat16(acc[c][reg]);
        float zv = acc[4+c][reg];
        if (use_hyp) zv += __bfloat162float(hypb[(size_t)n*HD + c*16 + col]);
        z[(size_t)n*HD + c*16 + col] = __float2bfloat16(zv);
      }
    }
  }
}

// pure-memory gather: out = [relu]( sum_j y_j / deg + z )   (bf16 io)
__global__ __launch_bounds__(256) void k_gather(
    const bf16* __restrict__ y, const bf16* __restrict__ z,
    const int* __restrict__ rowptr, const int* __restrict__ esrc,
    bf16* __restrict__ out, const int do_relu){
  const int lane  = threadIdx.x & 63;
  const int n     = blockIdx.x * 4 + (threadIdx.x >> 6);
  if (n >= NN) return;
  const int fq    = lane & 7;
  const int eslot = lane >> 3;
  const int r0 = rowptr[n], r1 = rowptr[n + 1];
  float a0[8] = {0,0,0,0,0,0,0,0};
  float a1[8] = {0,0,0,0,0,0,0,0};
  for (int base = r0; base < r1; base += 64){
    const int rem  = r1 - base;
    const int cdeg = rem < 64 ? rem : 64;
    const int sidx = (lane < cdeg) ? esrc[base + lane] : 0;
    const int rounds = (cdeg + 7) >> 3;
    for (int i = 0; i < rounds; i += 2){
      const int e0 = i*8 + eslot;
      const int e1 = e0 + 8;
      const int s0 = __shfl(sidx, e0, 64);
      const int s1 = __shfl(sidx, e1 & 63, 64);
      if (e0 < cdeg){
        const uint4 v = ((const uint4*)(y + (size_t)s0*HD))[fq];
        acc8(a0, v);
      }
      if (e1 < cdeg){
        const uint4 v = ((const uint4*)(y + (size_t)s1*HD))[fq];
        acc8(a1, v);
      }
    }
  }
  #pragma unroll
  for (int j = 0; j < 8; ++j){
    float s = a0[j] + a1[j];
    s += __shfl_xor(s, 8, 64);
    s += __shfl_xor(s, 16, 64);
    s += __shfl_xor(s, 32, 64);
    a0[j] = s;
  }
  if (eslot == 0){
    const int deg = r1 - r0;
    const float inv = deg > 0 ? 1.f / (float)deg : 0.f;
    const uint4 zv = ((const uint4*)(z + (size_t)n*HD))[fq];
    float zf[8];
    zf[0] = __uint_as_float(zv.x << 16); zf[1] = __uint_as_float(zv.x & 0xffff0000u);
    zf[2] = __uint_as_float(zv.y << 16); zf[3] = __uint_as_float(zv.y & 0xffff0000u);
    zf[4] = __uint_as_float(zv.z << 16); zf[5] = __uint_as_float(zv.z & 0xffff0000u);
    zf[6] = __uint_as_float(zv.w << 16); zf[7] = __uint_as_float(zv.w & 0xffff0000u);
    float o[8];
    #pragma unroll
    for (int j = 0; j < 8; ++j){
      o[j] = a0[j]*inv + zf[j];
      if (do_relu) o[j] = fmaxf(o[j], 0.f);
    }
    uint4 pv;
    pv.x = pack2(o[0], o[1]);
    pv.y = pack2(o[2], o[3]);
    pv.z = pack2(o[4], o[5]);
    pv.w = pack2(o[6], o[7]);
    ((uint4*)(out + (size_t)n*HD))[fq] = pv;
  }
}

// emb = h @ W_last + b_last ; out = [emb ; log_softmax(emb)]
__global__ __launch_bounds__(256) void k_final(
    const bf16* __restrict__ hin, const float* __restrict__ Wl,
    const float* __restrict__ bl, float* __restrict__ out){
  const int lane = threadIdx.x & 63;
  const int wid  = blockIdx.x * 4 + (threadIdx.x >> 6);
  const int nw   = gridDim.x * 4;
  const int c = lane < NC ? lane : 0;
  float w[HD];
  #pragma unroll
  for (int k = 0; k < HD; ++k) w[k] = Wl[k*NC + c];
  const float bb = bl[c];
  for (int n = wid; n < NN; n += nw){
    const float hv = __bfloat162float(hin[(size_t)n*HD + lane]);
    float c0 = bb, c1 = 0.f, c2 = 0.f, c3 = 0.f;
    #pragma unroll
    for (int k = 0; k < HD; k += 4){
      c0 += bcastf(hv, k  ) * w[k  ];
      c1 += bcastf(hv, k+1) * w[k+1];
      c2 += bcastf(hv, k+2) * w[k+2];
      c3 += bcastf(hv, k+3) * w[k+3];
    }
    const float acc = (c0 + c1) + (c2 + c3);
    float vmax = (lane < NC) ? acc : -3.4e38f;
    #pragma unroll
    for (int off = 32; off; off >>= 1)
      vmax = fmaxf(vmax, __shfl_xor(vmax, off, 64));
    float ex = (lane < NC) ? __expf(acc - vmax) : 0.f;
    float s = ex;
    #pragma unroll
    for (int off = 32; off; off >>= 1)
      s += __shfl_xor(s, off, 64);
    const float lsm = acc - vmax - __logf(s);
    if (lane < NC){
      out[(size_t)n*NC + lane]                 = acc;
      out[(size_t)NN*NC + (size_t)n*NC + lane] = lsm;
    }
  }
}

extern "C" void kernel_launch(void* const* d_in, const int* in_sizes, int n_in,
                              void* d_out, int out_size, void* d_ws, size_t ws_size,
                              hipStream_t stream){
  (void)in_sizes; (void)n_in; (void)out_size; (void)ws_size;
  const float* x_h    = (const float*)d_in[0];
  const float* pos    = (const float*)d_in[1];
  const int*   ei     = (const int*)  d_in[2];
  const float* W_pos  = (const float*)d_in[3];
  const float* b_pos  = (const float*)d_in[4];
  const float* W_init = (const float*)d_in[5];
  const float* b_init = (const float*)d_in[6];
  const float* W_l    = (const float*)d_in[7];
  const float* W_r    = (const float*)d_in[8];
  const float* b_conv = (const float*)d_in[9];
  const float* W_last = (const float*)d_in[10];
  const float* b_last = (const float*)d_in[11];
  float* out = (float*)d_out;

  char* p = (char*)d_ws;
  auto alloc = [&](size_t bytes)->char*{
    char* r = p; p += (bytes + 255) & ~(size_t)255; return r;
  };
  bf16* hb0    = (bf16*)alloc((size_t)NN*HD*2);
  bf16* hb1    = (bf16*)alloc((size_t)NN*HD*2);
  bf16* yb     = (bf16*)alloc((size_t)NN*HD*2);
  bf16* hypb   = (bf16*)alloc((size_t)NN*HD*2);
  int* cntp    = (int*)alloc((size_t)NN*16*4);
  int* cursorp = (int*)alloc((size_t)NN*16*4);
  int* rowptr  = (int*)alloc((size_t)(NN+1)*4);
  int* esrc    = (int*)alloc((size_t)NE*4);
  int* bsum    = (int*)alloc((size_t)NB*4);
  int* boff    = (int*)alloc((size_t)NB*4);

  hipMemsetAsync(cntp, 0, (size_t)NN*16*4, stream);
  k_count <<<(NE + 255)/256, 256, 0, stream>>>(ei, cntp);
  k_bsum  <<<NB, 256, 0, stream>>>(cntp, bsum);
  k_bscan <<<1, 256, 0, stream>>>(bsum, boff);
  k_rowptr<<<NB, 256, 0, stream>>>(cntp, boff, rowptr, cursorp);
  k_fill  <<<((NE + 2047)/2048)*8, 256, 0, stream>>>(ei, cursorp, esrc);
  k_init  <<<1024, 256, 0, stream>>>(x_h, pos, W_init, b_init, W_pos, b_pos, hb0, hypb);

  bf16* cur = hb0;
  bf16* nxt = hb1;
  for (int l = 0; l < 3; ++l){
    const int last = (l == 2);
    // y -> yb ; z -> nxt (includes +hyp when not last layer)
    k_xform <<<782, 256, 0, stream>>>(cur, W_l + l*HD*HD, W_r + l*HD*HD,
                                      b_conv + l*HD, hypb, !last, yb, nxt);
    // out -> in-place over nxt (z); relu when not last layer
    k_gather<<<(NN + 3)/4, 256, 0, stream>>>(yb, nxt, rowptr, esrc, nxt, !last);
    bf16* t = cur; cur = nxt; nxt = t;
  }
  k_final <<<512, 256, 0, stream>>>(cur, W_last, b_last, out);
}

// Round 8
// 315.705 us; speedup vs baseline: 1.5096x; 1.1125x over previous
//
#include <hip/hip_runtime.h>
#include <hip/hip_bf16.h>

#define NN 50000
#define NE 800000
#define FIN 128
#define HD 64
#define NC 40
#define NB 196      // ceil(NN/256)
#define RSPAN 6250  // NN/8 (dst range per blockIdx&7 class)

typedef __hip_bfloat16 bf16;
typedef __attribute__((ext_vector_type(8))) short bf16x8;   // 8 bf16 in 4 VGPRs
typedef __attribute__((ext_vector_type(4))) float f32x4;

// accumulate 8 bf16 (one uint4) into fp32 bank
__device__ __forceinline__ void acc8(float* a, uint4 v){
  a[0] += __uint_as_float(v.x << 16); a[1] += __uint_as_float(v.x & 0xffff0000u);
  a[2] += __uint_as_float(v.y << 16); a[3] += __uint_as_float(v.y & 0xffff0000u);
  a[4] += __uint_as_float(v.z << 16); a[5] += __uint_as_float(v.z & 0xffff0000u);
  a[6] += __uint_as_float(v.w << 16); a[7] += __uint_as_float(v.w & 0xffff0000u);
}

__device__ __forceinline__ unsigned pack2(float lo, float hi){
  union { bf16 b; unsigned short u; } a, b;
  a.b = __float2bfloat16(lo);
  b.b = __float2bfloat16(hi);
  return (unsigned)a.u | ((unsigned)b.u << 16);
}

__device__ __forceinline__ short f2bf_bits(float f){
  union { bf16 b; short s; } u;
  u.b = __float2bfloat16(f);
  return u.s;
}

// counters padded to 1 per 64B line (d<<4): breaks same-line atomic serialization
__global__ void k_count(const int* __restrict__ ei, int* __restrict__ cntp){
  int e = blockIdx.x*256 + threadIdx.x;
  if (e < NE) atomicAdd(&cntp[ei[NE + e] << 4], 1);
}

__global__ void k_bsum(const int* __restrict__ cntp, int* __restrict__ bsum){
  const int t = threadIdx.x;
  const int i = blockIdx.x*256 + t;
  int v = (i < NN) ? cntp[i << 4] : 0;
  #pragma unroll
  for (int off = 32; off; off >>= 1) v += __shfl_xor(v, off, 64);
  __shared__ int sw[4];
  if ((t & 63) == 0) sw[t >> 6] = v;
  __syncthreads();
  if (t == 0) bsum[blockIdx.x] = sw[0] + sw[1] + sw[2] + sw[3];
}

__global__ void k_bscan(const int* __restrict__ bsum, int* __restrict__ boff){
  __shared__ int sh[256];
  const int t = threadIdx.x;
  int v = (t < NB) ? bsum[t] : 0;
  sh[t] = v;
  __syncthreads();
  #pragma unroll
  for (int off = 1; off < 256; off <<= 1){
    int a = (t >= off) ? sh[t - off] : 0;
    __syncthreads();
    sh[t] += a;
    __syncthreads();
  }
  if (t < NB) boff[t] = sh[t] - v;   // exclusive
}

__global__ void k_rowptr(const int* __restrict__ cntp, const int* __restrict__ boff,
                         int* __restrict__ rowptr, int* __restrict__ cursorp){
  __shared__ int sh[256];
  const int t = threadIdx.x;
  const int i = blockIdx.x*256 + t;
  int v = (i < NN) ? cntp[i << 4] : 0;
  sh[t] = v;
  __syncthreads();
  #pragma unroll
  for (int off = 1; off < 256; off <<= 1){
    int a = (t >= off) ? sh[t - off] : 0;
    __syncthreads();
    sh[t] += a;
    __syncthreads();
  }
  if (i < NN){
    int excl = sh[t] - v + boff[blockIdx.x];
    rowptr[i] = excl;
    cursorp[i << 4] = excl;
  }
  if (i == 0) rowptr[NN] = NE;
}

// range-filtered scatter: block b reads edge-chunk b>>3, keeps dst in range b&7.
__global__ void k_fill(const int* __restrict__ ei, int* __restrict__ cursorp,
                       int* __restrict__ esrc){
  const int chunk = blockIdx.x >> 3;
  const int lo    = (blockIdx.x & 7) * RSPAN;
  const int hi    = lo + RSPAN;
  int e = chunk * 2048 + threadIdx.x;
  #pragma unroll
  for (int j = 0; j < 8; ++j, e += 256){
    if (e < NE){
      const int d = ei[NE + e];
      if (d >= lo && d < hi){
        const int p = atomicAdd(&cursorp[d << 4], 1);
        esrc[p] = ei[e];
      }
    }
  }
}

// MFMA init: h0 = bf16(x@W_init + b_init) ; hyp = bf16(tanh(pos@W_pos + b_pos))
// Wave per 16-node tile. x K=128 (4 K-frags, fp32->bf16 inline); pos K=16
// zero-padded to one K=32 frag in both A and B.
__global__ __launch_bounds__(256) void k_init(
    const float* __restrict__ x, const float* __restrict__ pos,
    const float* __restrict__ Wi, const float* __restrict__ bi,
    const float* __restrict__ Wp, const float* __restrict__ bp,
    bf16* __restrict__ h0b, bf16* __restrict__ hypb){
  const int lane = threadIdx.x & 63;
  const int quad = lane >> 4;
  const int col  = lane & 15;
  const int wid  = blockIdx.x * 4 + (threadIdx.x >> 6);
  const int nw   = gridDim.x * 4;

  bf16x8 wif[4][4];   // [col-tile][K-frag]
  #pragma unroll
  for (int ct = 0; ct < 4; ++ct)
    #pragma unroll
    for (int kf = 0; kf < 4; ++kf)
      #pragma unroll
      for (int j = 0; j < 8; ++j)
        wif[ct][kf][j] = f2bf_bits(Wi[(kf*32 + quad*8 + j)*HD + ct*16 + col]);
  bf16x8 wpf[4];
  #pragma unroll
  for (int ct = 0; ct < 4; ++ct)
    #pragma unroll
    for (int j = 0; j < 8; ++j){
      const int k = quad*8 + j;
      wpf[ct][j] = (k < 16) ? f2bf_bits(Wp[k*HD + ct*16 + col]) : (short)0;
    }
  float bih[4], bph[4];
  #pragma unroll
  for (int c = 0; c < 4; ++c){ bih[c] = bi[c*16 + col]; bph[c] = bp[c*16 + col]; }

  for (int t = wid; t < NN/16; t += nw){
    const int n0 = t * 16;
    bf16x8 af[4];
    #pragma unroll
    for (int kf = 0; kf < 4; ++kf){
      const float* xr = x + (size_t)(n0 + col)*FIN + kf*32 + quad*8;
      const float4 f0 = *(const float4*)xr;
      const float4 f1 = *(const float4*)(xr + 4);
      af[kf][0] = f2bf_bits(f0.x); af[kf][1] = f2bf_bits(f0.y);
      af[kf][2] = f2bf_bits(f0.z); af[kf][3] = f2bf_bits(f0.w);
      af[kf][4] = f2bf_bits(f1.x); af[kf][5] = f2bf_bits(f1.y);
      af[kf][6] = f2bf_bits(f1.z); af[kf][7] = f2bf_bits(f1.w);
    }
    bf16x8 ap;
    #pragma unroll
    for (int j = 0; j < 8; ++j) ap[j] = 0;
    if (quad < 2){
      const float* pr = pos + (size_t)(n0 + col)*16 + quad*8;
      const float4 p0 = *(const float4*)pr;
      const float4 p1 = *(const float4*)(pr + 4);
      ap[0] = f2bf_bits(p0.x); ap[1] = f2bf_bits(p0.y);
      ap[2] = f2bf_bits(p0.z); ap[3] = f2bf_bits(p0.w);
      ap[4] = f2bf_bits(p1.x); ap[5] = f2bf_bits(p1.y);
      ap[6] = f2bf_bits(p1.z); ap[7] = f2bf_bits(p1.w);
    }
    f32x4 ah[4], app[4];
    #pragma unroll
    for (int c = 0; c < 4; ++c){
      ah[c]  = (f32x4){bih[c], bih[c], bih[c], bih[c]};
      app[c] = (f32x4){bph[c], bph[c], bph[c], bph[c]};
    }
    #pragma unroll
    for (int ct = 0; ct < 4; ++ct){
      #pragma unroll
      for (int kf = 0; kf < 4; ++kf)
        ah[ct] = __builtin_amdgcn_mfma_f32_16x16x32_bf16(af[kf], wif[ct][kf], ah[ct], 0, 0, 0);
      app[ct] = __builtin_amdgcn_mfma_f32_16x16x32_bf16(ap, wpf[ct], app[ct], 0, 0, 0);
    }
    #pragma unroll
    for (int reg = 0; reg < 4; ++reg){
      const int n = n0 + quad*4 + reg;
      #pragma unroll
      for (int c = 0; c < 4; ++c){
        h0b[(size_t)n*HD + c*16 + col]  = __float2bfloat16(ah[c][reg]);
        hypb[(size_t)n*HD + c*16 + col] = __float2bfloat16(tanhf(app[c][reg]));
      }
    }
  }
}

// MFMA dense transforms: y = h@Wl ; z = h@Wr + b (+hyp)   (bf16 io, fp32 accum)
__global__ __launch_bounds__(256) void k_xform(
    const bf16* __restrict__ h, const float* __restrict__ Wl,
    const float* __restrict__ Wr, const float* __restrict__ bc,
    const bf16* __restrict__ hypb, const int use_hyp,
    bf16* __restrict__ y, bf16* __restrict__ z){
  const int lane = threadIdx.x & 63;
  const int quad = lane >> 4;
  const int col  = lane & 15;
  const int wid  = blockIdx.x * 4 + (threadIdx.x >> 6);
  const int nw   = gridDim.x * 4;

  bf16x8 bfr[8][2];
  #pragma unroll
  for (int ct = 0; ct < 8; ++ct){
    const float* W = (ct < 4) ? Wl : Wr;
    const int nc = (ct & 3) * 16 + col;
    #pragma unroll
    for (int kf = 0; kf < 2; ++kf)
      #pragma unroll
      for (int j = 0; j < 8; ++j)
        bfr[ct][kf][j] = f2bf_bits(W[(kf*32 + quad*8 + j)*HD + nc]);
  }
  float zb[4];
  #pragma unroll
  for (int c = 0; c < 4; ++c) zb[c] = bc[c*16 + col];

  for (int t = wid; t < NN/16; t += nw){
    const int n0 = t * 16;
    union { uint4 u; bf16x8 v; } a0, a1;
    a0.u = *(const uint4*)(h + (size_t)(n0 + col)*HD + quad*8);
    a1.u = *(const uint4*)(h + (size_t)(n0 + col)*HD + 32 + quad*8);
    f32x4 acc[8];
    #pragma unroll
    for (int c = 0; c < 4; ++c) acc[c] = (f32x4){0.f, 0.f, 0.f, 0.f};
    #pragma unroll
    for (int c = 0; c < 4; ++c) acc[4+c] = (f32x4){zb[c], zb[c], zb[c], zb[c]};
    #pragma unroll
    for (int ct = 0; ct < 8; ++ct){
      acc[ct] = __builtin_amdgcn_mfma_f32_16x16x32_bf16(a0.v, bfr[ct][0], acc[ct], 0, 0, 0);
      acc[ct] = __builtin_amdgcn_mfma_f32_16x16x32_bf16(a1.v, bfr[ct][1], acc[ct], 0, 0, 0);
    }
    #pragma unroll
    for (int reg = 0; reg < 4; ++reg){
      const int n = n0 + quad*4 + reg;
      #pragma unroll
      for (int c = 0; c < 4; ++c){
        y[(size_t)n*HD + c*16 + col] = __float2bfloat16(acc[c][reg]);
        float zv = acc[4+c][reg];
        if (use_hyp) zv += __bfloat162float(hypb[(size_t)n*HD + c*16 + col]);
        z[(size_t)n*HD + c*16 + col] = __float2bfloat16(zv);
      }
    }
  }
}

// pure-memory gather: out = [relu]( sum_j y_j / deg + z )   (bf16 io)
__global__ __launch_bounds__(256) void k_gather(
    const bf16* __restrict__ y, const bf16* __restrict__ z,
    const int* __restrict__ rowptr, const int* __restrict__ esrc,
    bf16* __restrict__ out, const int do_relu){
  const int lane  = threadIdx.x & 63;
  const int n     = blockIdx.x * 4 + (threadIdx.x >> 6);
  if (n >= NN) return;
  const int fq    = lane & 7;
  const int eslot = lane >> 3;
  const int r0 = rowptr[n], r1 = rowptr[n + 1];
  float a0[8] = {0,0,0,0,0,0,0,0};
  float a1[8] = {0,0,0,0,0,0,0,0};
  for (int base = r0; base < r1; base += 64){
    const int rem  = r1 - base;
    const int cdeg = rem < 64 ? rem : 64;
    const int sidx = (lane < cdeg) ? esrc[base + lane] : 0;
    const int rounds = (cdeg + 7) >> 3;
    for (int i = 0; i < rounds; i += 2){
      const int e0 = i*8 + eslot;
      const int e1 = e0 + 8;
      const int s0 = __shfl(sidx, e0, 64);
      const int s1 = __shfl(sidx, e1 & 63, 64);
      if (e0 < cdeg){
        const uint4 v = ((const uint4*)(y + (size_t)s0*HD))[fq];
        acc8(a0, v);
      }
      if (e1 < cdeg){
        const uint4 v = ((const uint4*)(y + (size_t)s1*HD))[fq];
        acc8(a1, v);
      }
    }
  }
  #pragma unroll
  for (int j = 0; j < 8; ++j){
    float s = a0[j] + a1[j];
    s += __shfl_xor(s, 8, 64);
    s += __shfl_xor(s, 16, 64);
    s += __shfl_xor(s, 32, 64);
    a0[j] = s;
  }
  if (eslot == 0){
    const int deg = r1 - r0;
    const float inv = deg > 0 ? 1.f / (float)deg : 0.f;
    const uint4 zv = ((const uint4*)(z + (size_t)n*HD))[fq];
    float zf[8];
    zf[0] = __uint_as_float(zv.x << 16); zf[1] = __uint_as_float(zv.x & 0xffff0000u);
    zf[2] = __uint_as_float(zv.y << 16); zf[3] = __uint_as_float(zv.y & 0xffff0000u);
    zf[4] = __uint_as_float(zv.z << 16); zf[5] = __uint_as_float(zv.z & 0xffff0000u);
    zf[6] = __uint_as_float(zv.w << 16); zf[7] = __uint_as_float(zv.w & 0xffff0000u);
    float o[8];
    #pragma unroll
    for (int j = 0; j < 8; ++j){
      o[j] = a0[j]*inv + zf[j];
      if (do_relu) o[j] = fmaxf(o[j], 0.f);
    }
    uint4 pv;
    pv.x = pack2(o[0], o[1]);
    pv.y = pack2(o[2], o[3]);
    pv.z = pack2(o[4], o[5]);
    pv.w = pack2(o[6], o[7]);
    ((uint4*)(out + (size_t)n*HD))[fq] = pv;
  }
}

// MFMA final: emb = h@W_last + b_last ; out = [emb ; log_softmax(emb)]
// 3 col-tiles cover 48 cols; cols 40..47 get W=0, bias=-1e30 (vanish in softmax).
// Per-node reduce = shfl_xor 1/2/4/8 within the 16-lane col group.
__global__ __launch_bounds__(256) void k_final(
    const bf16* __restrict__ hin, const float* __restrict__ Wl,
    const float* __restrict__ bl, float* __restrict__ out){
  const int lane = threadIdx.x & 63;
  const int quad = lane >> 4;
  const int col  = lane & 15;
  const int wid  = blockIdx.x * 4 + (threadIdx.x >> 6);
  const int nw   = gridDim.x * 4;

  bf16x8 wf[3][2];
  float bb[3];
  #pragma unroll
  for (int ct = 0; ct < 3; ++ct){
    const int nc = ct*16 + col;
    const bool valid = nc < NC;
    bb[ct] = valid ? bl[nc] : -1e30f;
    #pragma unroll
    for (int kf = 0; kf < 2; ++kf)
      #pragma unroll
      for (int j = 0; j < 8; ++j)
        wf[ct][kf][j] = valid ? f2bf_bits(Wl[(kf*32 + quad*8 + j)*NC + nc]) : (short)0;
  }

  for (int t = wid; t < NN/16; t += nw){
    const int n0 = t * 16;
    union { uint4 u; bf16x8 v; } a0, a1;
    a0.u = *(const uint4*)(hin + (size_t)(n0 + col)*HD + quad*8);
    a1.u = *(const uint4*)(hin + (size_t)(n0 + col)*HD + 32 + quad*8);
    f32x4 acc[3];
    #pragma unroll
    for (int ct = 0; ct < 3; ++ct){
      acc[ct] = (f32x4){bb[ct], bb[ct], bb[ct], bb[ct]};
      acc[ct] = __builtin_amdgcn_mfma_f32_16x16x32_bf16(a0.v, wf[ct][0], acc[ct], 0, 0, 0);
      acc[ct] = __builtin_amdgcn_mfma_f32_16x16x32_bf16(a1.v, wf[ct][1], acc[ct], 0, 0, 0);
    }
    #pragma unroll
    for (int reg = 0; reg < 4; ++reg){
      const float e0 = acc[0][reg], e1 = acc[1][reg], e2 = acc[2][reg];
      float vmax = fmaxf(fmaxf(e0, e1), e2);
      vmax = fmaxf(vmax, __shfl_xor(vmax, 1, 64));
      vmax = fmaxf(vmax, __shfl_xor(vmax, 2, 64));
      vmax = fmaxf(vmax, __shfl_xor(vmax, 4, 64));
      vmax = fmaxf(vmax, __shfl_xor(vmax, 8, 64));
      float s = __expf(e0 - vmax) + __expf(e1 - vmax) + __expf(e2 - vmax);
      s += __shfl_xor(s, 1, 64);
      s += __shfl_xor(s, 2, 64);
      s += __shfl_xor(s, 4, 64);
      s += __shfl_xor(s, 8, 64);
      const float off = vmax + __logf(s);
      const int n = n0 + quad*4 + reg;
      #pragma unroll
      for (int ct = 0; ct < 3; ++ct){
        const int nc = ct*16 + col;
        if (nc < NC){
          const float e = acc[ct][reg];
          out[(size_t)n*NC + nc]                 = e;
          out[(size_t)NN*NC + (size_t)n*NC + nc] = e - off;
        }
      }
    }
  }
}

extern "C" void kernel_launch(void* const* d_in, const int* in_sizes, int n_in,
                              void* d_out, int out_size, void* d_ws, size_t ws_size,
                              hipStream_t stream){
  (void)in_sizes; (void)n_in; (void)out_size; (void)ws_size;
  const float* x_h    = (const float*)d_in[0];
  const float* pos    = (const float*)d_in[1];
  const int*   ei     = (const int*)  d_in[2];
  const float* W_pos  = (const float*)d_in[3];
  const float* b_pos  = (const float*)d_in[4];
  const float* W_init = (const float*)d_in[5];
  const float* b_init = (const float*)d_in[6];
  const float* W_l    = (const float*)d_in[7];
  const float* W_r    = (const float*)d_in[8];
  const float* b_conv = (const float*)d_in[9];
  const float* W_last = (const float*)d_in[10];
  const float* b_last = (const float*)d_in[11];
  float* out = (float*)d_out;

  char* p = (char*)d_ws;
  auto alloc = [&](size_t bytes)->char*{
    char* r = p; p += (bytes + 255) & ~(size_t)255; return r;
  };
  bf16* hb0    = (bf16*)alloc((size_t)NN*HD*2);
  bf16* hb1    = (bf16*)alloc((size_t)NN*HD*2);
  bf16* yb     = (bf16*)alloc((size_t)NN*HD*2);
  bf16* hypb   = (bf16*)alloc((size_t)NN*HD*2);
  int* cntp    = (int*)alloc((size_t)NN*16*4);
  int* cursorp = (int*)alloc((size_t)NN*16*4);
  int* rowptr  = (int*)alloc((size_t)(NN+1)*4);
  int* esrc    = (int*)alloc((size_t)NE*4);
  int* bsum    = (int*)alloc((size_t)NB*4);
  int* boff    = (int*)alloc((size_t)NB*4);

  hipMemsetAsync(cntp, 0, (size_t)NN*16*4, stream);
  k_count <<<(NE + 255)/256, 256, 0, stream>>>(ei, cntp);
  k_bsum  <<<NB, 256, 0, stream>>>(cntp, bsum);
  k_bscan <<<1, 256, 0, stream>>>(bsum, boff);
  k_rowptr<<<NB, 256, 0, stream>>>(cntp, boff, rowptr, cursorp);
  k_fill  <<<((NE + 2047)/2048)*8, 256, 0, stream>>>(ei, cursorp, esrc);
  k_init  <<<782, 256, 0, stream>>>(x_h, pos, W_init, b_init, W_pos, b_pos, hb0, hypb);

  bf16* cur = hb0;
  bf16* nxt = hb1;
  for (int l = 0; l < 3; ++l){
    const int last = (l == 2);
    k_xform <<<782, 256, 0, stream>>>(cur, W_l + l*HD*HD, W_r + l*HD*HD,
                                      b_conv + l*HD, hypb, !last, yb, nxt);
    k_gather<<<(NN + 3)/4, 256, 0, stream>>>(yb, nxt, rowptr, esrc, nxt, !last);
    bf16* t = cur; cur = nxt; nxt = t;
  }
  k_final <<<782, 256, 0, stream>>>(cur, W_last, b_last, out);
}